// Round 5
// baseline (1330.374 us; speedup 1.0000x reference)
//
#include <hip/hip_runtime.h>
#include <stdint.h>

#define M_DIM 8192   // BATCH*SEQ = 4*2048
#define N_DIM 4096
#define K_DIM 4096
#define BM 128
#define BN 128
#define BK 64

typedef int v4i __attribute__((ext_vector_type(4)));
typedef unsigned u32;

__device__ __forceinline__ void gll16(const void* g, void* l) {
  __builtin_amdgcn_global_load_lds(
      (const __attribute__((address_space(1))) void*)g,
      (__attribute__((address_space(3))) void*)l, 16, 0, 0);
}

__device__ __forceinline__ u32 pack4(const int4 v) {
  return (v.x & 0xffu) | ((v.y & 0xffu) << 8) | ((v.z & 0xffu) << 16) |
         ((u32)(v.w & 0xffu) << 24);
}

// ---------------------------------------------------------------------------
// Header-based dtype detection: first 4 KB of X is in-bounds under both
// hypotheses; i32 materialization iff every word is a sign-extended int8.
// ---------------------------------------------------------------------------
__device__ __forceinline__ bool hdr_is_i32(const int* __restrict__ X, int tid,
                                           int* ok) {
  if (tid == 0) *ok = 1;
  __syncthreads();
  int good = 1;
  for (int i = tid; i < 1024; i += 256) {
    const int w = X[i];
    good &= (w == (int)(int8_t)(w & 0xff));
  }
  if (!good) atomicAnd(ok, 0);
  __syncthreads();
  return *ok != 0;
}

// Standalone detect (fallback paths only; writes flag for gemm_inA).
__global__ __launch_bounds__(256) void detect_i32(const int* __restrict__ X,
                                                  u32* __restrict__ flag) {
  __shared__ int ok;
  const bool i32 = hdr_is_i32(X, threadIdx.x, &ok);
  if (threadIdx.x == 0) *flag = i32 ? 1u : 0u;
}

// ---------------------------------------------------------------------------
// pack_x_f: X -> packed int8 bytes; dtype self-detected from header.
// ---------------------------------------------------------------------------
__global__ __launch_bounds__(256) void pack_x_f(const void* __restrict__ Xin,
                                                u32* __restrict__ out) {
  __shared__ int ok;
  const bool i32 = hdr_is_i32((const int*)Xin, threadIdx.x, &ok);
  const int base = blockIdx.x * 1024 + threadIdx.x;
  if (i32) {
    const int4* in = (const int4*)Xin;  // 128 MB source (valid when int32)
#pragma unroll
    for (int j = 0; j < 4; ++j) {
      const int idx = base + j * 256;
      out[idx] = pack4(in[idx]);
    }
  } else {
    const u32* in = (const u32*)Xin;    // 32 MB source (already bytes)
#pragma unroll
    for (int j = 0; j < 4; ++j) {
      const int idx = base + j * 256;
      out[idx] = in[idx];
    }
  }
}

// ---------------------------------------------------------------------------
// packT_w_f: W [K][N] -> WT int8 [N][K], 64x64 tiles; dtype from X header
// (X and W share the same materialization).
// ---------------------------------------------------------------------------
__global__ __launch_bounds__(256) void packT_w_f(const void* __restrict__ Wv,
                                                 int8_t* __restrict__ WT,
                                                 const int* __restrict__ Xhdr) {
  __shared__ u32 lds[64 * 21];
  __shared__ int ok;
  const int tid = threadIdx.x;
  const bool i32 = hdr_is_i32(Xhdr, tid, &ok);
  const int tk = blockIdx.x & 63;   // k-tile
  const int tn = blockIdx.x >> 6;   // n-tile
  const int k0 = tk * 64, n0 = tn * 64;

#pragma unroll
  for (int j = 0; j < 4; ++j) {
    const int id = j * 256 + tid;
    const int k = id >> 4, c = id & 15;
    u32 word;
    if (i32) {
      const int4 v =
          *(const int4*)((const int*)Wv + (size_t)(k0 + k) * N_DIM + n0 + c * 4);
      word = pack4(v);
    } else {
      word = *(const u32*)((const int8_t*)Wv + (size_t)(k0 + k) * N_DIM + n0 +
                           c * 4);
    }
    lds[k * 21 + c] = word;  // bytes of W[k0+k][n0+c*4 .. +4]
  }
  __syncthreads();
  const int kd = tid & 15, nq = tid >> 4;
  const u32 d0 = lds[(kd * 4 + 0) * 21 + nq];
  const u32 d1 = lds[(kd * 4 + 1) * 21 + nq];
  const u32 d2 = lds[(kd * 4 + 2) * 21 + nq];
  const u32 d3 = lds[(kd * 4 + 3) * 21 + nq];
  u32* outp = (u32*)WT;
#pragma unroll
  for (int i = 0; i < 4; ++i) {
    const u32 e = ((d0 >> (8 * i)) & 0xffu) | (((d1 >> (8 * i)) & 0xffu) << 8) |
                  (((d2 >> (8 * i)) & 0xffu) << 16) |
                  (((d3 >> (8 * i)) & 0xffu) << 24);
    const int n = n0 + nq * 4 + i;
    outp[(size_t)n * (K_DIM / 4) + (k0 / 4) + kd] = e;
  }
}

// ---------------------------------------------------------------------------
// epilogue (128² fallback): C/D layout col = lane&15, row = quad*4 + reg.
// ---------------------------------------------------------------------------
__device__ __forceinline__ void epilogue(const v4i acc[4][4], float a,
                                         const float* __restrict__ bScale,
                                         int* __restrict__ Y, int bm, int bn,
                                         int wm, int wn, int quad, int l16) {
  const int nBase = bn * BN + wn * 64 + l16;
  float bs[4];
#pragma unroll
  for (int ni = 0; ni < 4; ++ni) bs[ni] = bScale[nBase + ni * 16];
#pragma unroll
  for (int mi = 0; mi < 4; ++mi) {
    const int m0 = bm * BM + wm * 64 + mi * 16 + quad * 4;
#pragma unroll
    for (int r = 0; r < 4; ++r) {
      int* row = Y + (size_t)(m0 + r) * N_DIM + nBase;
#pragma unroll
      for (int ni = 0; ni < 4; ++ni) {
        float v = ((float)acc[mi][ni][r] * a) * bs[ni];
        v = rintf(v);
        v = fminf(fmaxf(v, -128.f), 127.f);
        row[ni * 16] = (int)v;
      }
    }
  }
}

// ---- gemm_256 helpers -----------------------------------------------------
__device__ __forceinline__ void rd4(v4i* f, const int8_t* base, int off) {
#pragma unroll
  for (int i = 0; i < 4; ++i) f[i] = *(const v4i*)(base + off + i * 1024);
}

__device__ __forceinline__ void mfma16(v4i acc[8][4], int row, const v4i* a,
                                       const v4i* b) {
#pragma unroll
  for (int mi = 0; mi < 4; ++mi)
#pragma unroll
    for (int ni = 0; ni < 4; ++ni)
      acc[row + mi][ni] = __builtin_amdgcn_mfma_i32_16x16x64_i8(
          a[mi], b[ni], acc[row + mi][ni], 0, 0, 0);
}

// ---------------------------------------------------------------------------
// gemm_256: 256x256 tile, 8 waves (2M x 4N), mfma_i32_16x16x64_i8
// (HW-verified conflict-free fragment layout).
// R5 change: LDS cut to a 2-slot double buffer (64 KB) -> 2 BLOCKS/CU
// (grid 512 = exactly 2/CU, 4 waves/SIMD). R1/R3/R4 all pinned MfmaUtil
// at 39% with 1 block/CU regardless of in-block schedule; the missing
// overlap is CROSS-BLOCK (m97/m114 mechanism): while this block drains
// vmcnt(0)+barrier, the co-resident block's waves feed the MFMA pipe.
//  - per kstep: stage next slot -> 12 ds_reads + 32 MFMA -> vmcnt(0)+barrier.
//  - T2 XOR swizzle via pre-swizzled global source + swizzled ds_read.
//  - T5 setprio; T1 bijective XCD swizzle (512%8==0).
//  - __launch_bounds__(512,4) caps VGPR at 128 for the 2-block occupancy.
// ---------------------------------------------------------------------------
__global__ __launch_bounds__(512, 4) void gemm_256(
    const int8_t* __restrict__ X, const int8_t* __restrict__ WT,
    const float* __restrict__ aScale, const float* __restrict__ bScale,
    int* __restrict__ Y) {
  __shared__ __align__(16) int8_t lds[65536];  // A dbuf 32KB | B dbuf 32KB
  const int tid = threadIdx.x;
  const int lane = tid & 63;
  const int wave = tid >> 6;
  const int quad = lane >> 4, l16 = lane & 15;
  const int wm = wave >> 2, wn = wave & 3;  // 2 x 4 wave grid

  // XCD-aware bijective swizzle: nwg=512, 64 blocks/XCD
  const int swzb = (blockIdx.x & 7) * 64 + (blockIdx.x >> 3);
  const int bn = swzb & 15, bm = swzb >> 4;  // bn inner: A-panel reuse per XCD

  // write-side swizzle selector: row = tid>>2  ->  (row>>1)&3 = (tid>>3)&3
  const int clog = (((tid & 3) ^ ((tid >> 3) & 3)) << 4);
  // read-side: row = {wm*128|wn*64} + {mi|ni}*16 + l16 -> (row>>1)&3 = (l16>>1)&3
  const int pc = quad ^ ((l16 >> 1) & 3);

  const int8_t* xa = X + (size_t)(bm * 256 + (tid >> 2)) * K_DIM + clog;
  const int8_t* xb = WT + (size_t)(bn * 256 + (tid >> 2)) * K_DIM + clog;
  int8_t* ldsA = lds + tid * 16;           // linear DMA dest, round1 at +8192
  int8_t* ldsB = lds + 32768 + tid * 16;
  const int8_t* aBase = lds + (wm * 128 + l16) * 64 + pc * 16;
  const int8_t* bBase = lds + 32768 + (wn * 64 + l16) * 64 + pc * 16;

  v4i acc[8][4] = {};

  // prologue: stage kstep 0 into slot 0
  gll16(xa, ldsA);
  gll16(xa + (size_t)128 * K_DIM, ldsA + 8192);
  gll16(xb, ldsB);
  gll16(xb + (size_t)128 * K_DIM, ldsB + 8192);
  asm volatile("s_waitcnt vmcnt(0)" ::: "memory");
  __builtin_amdgcn_s_barrier();

  for (int g = 0; g < 64; ++g) {
    const int soff = (g & 1) << 14;
    // stage kstep g+1 into the other slot (writes never touch the read slot;
    // end-of-kstep vmcnt(0)+barrier publishes before slot reuse)
    if (g < 63) {
      const int poff = ((g + 1) & 1) << 14;
      const int8_t* sa = xa + (size_t)(g + 1) * 64;
      const int8_t* sb = xb + (size_t)(g + 1) * 64;
      gll16(sa, ldsA + poff);
      gll16(sa + (size_t)128 * K_DIM, ldsA + poff + 8192);
      gll16(sb, ldsB + poff);
      gll16(sb + (size_t)128 * K_DIM, ldsB + poff + 8192);
    }
    // fragment reads + 32 MFMA; compiler interleaves with fine-grained lgkmcnt
    v4i bf[4], af[4], ag[4];
    rd4(bf, bBase, soff);
    rd4(af, aBase, soff);
    __builtin_amdgcn_s_setprio(1);
    mfma16(acc, 0, af, bf);
    rd4(ag, aBase, soff + 4096);  // second-half A hides under first 16 MFMAs
    mfma16(acc, 4, ag, bf);
    __builtin_amdgcn_s_setprio(0);
    // drain this kstep's stage; co-resident block's waves hide the stall
    asm volatile("s_waitcnt vmcnt(0)" ::: "memory");
    __builtin_amdgcn_s_barrier();
  }

  // ---- epilogue: col = lane&15, row = quad*4 + reg ----
  const float a = aScale[0];
  const int nBase = bn * 256 + wn * 64 + l16;
  float bs[4];
#pragma unroll
  for (int ni = 0; ni < 4; ++ni) bs[ni] = bScale[nBase + ni * 16];
#pragma unroll
  for (int mi = 0; mi < 8; ++mi) {
    const int m0 = bm * 256 + wm * 128 + mi * 16 + quad * 4;
#pragma unroll
    for (int r = 0; r < 4; ++r) {
      int* row = Y + (size_t)(m0 + r) * N_DIM + nBase;
#pragma unroll
      for (int ni = 0; ni < 4; ++ni) {
        float v = ((float)acc[mi][ni][r] * a) * bs[ni];
        v = rintf(v);
        v = fminf(fmaxf(v, -128.f), 127.f);
        row[ni * 16] = (int)v;
      }
    }
  }
}

// ---------------------------------------------------------------------------
// gemm_inA (fallback when ws only fits WT): A read from X (dtype by flag,
// packed in-kernel), B from packed WT. GEMM never writes ws -> no race.
// ---------------------------------------------------------------------------
__global__ __launch_bounds__(256) void gemm_inA(
    const void* __restrict__ Xv, const int8_t* __restrict__ WT,
    const float* __restrict__ aScale, const float* __restrict__ bScale,
    int* __restrict__ Y, const u32* __restrict__ flag) {
  __shared__ __align__(16) int8_t As[BM * BK];
  __shared__ __align__(16) int8_t Bs[BN * BK];
  const bool i32 = (*flag != 0);
  const int tid = threadIdx.x;
  const int lane = tid & 63, wave = tid >> 6;
  const int quad = lane >> 4, l16 = lane & 15;
  const int wm = wave & 1, wn = wave >> 1;
  const int bn = blockIdx.x & 31;
  const int bm = blockIdx.x >> 5;

  const int r0 = tid >> 2;
  const int c0 = (tid & 3) * 16;   // k offset (elements) within BK
  const int8_t* Bg0 = WT + (size_t)(bn * BN + r0) * K_DIM + c0;
  const int8_t* Bg1 = Bg0 + (size_t)64 * K_DIM;
  int8_t* Al0 = As + tid * 16;
  int8_t* Al1 = Al0 + 4096;
  int8_t* Bl0 = Bs + tid * 16;
  int8_t* Bl1 = Bl0 + 4096;

  v4i acc[4][4] = {};
  const int8_t* aLds = As + (wm * 64 + l16) * BK + quad * 16;
  const int8_t* bLds = Bs + (wn * 64 + l16) * BK + quad * 16;

  if (i32) {
    const int* Xg0 = (const int*)Xv + (size_t)(bm * BM + r0) * K_DIM + c0;
    const int* Xg1 = Xg0 + (size_t)64 * K_DIM;
    for (int k0 = 0; k0 < K_DIM; k0 += BK) {
      gll16(Bg0 + k0, Bl0);
      gll16(Bg1 + k0, Bl1);
      const int4* p0 = (const int4*)(Xg0 + k0);
      const int4* p1 = (const int4*)(Xg1 + k0);
      uint4 w0, w1;
      w0.x = pack4(p0[0]); w0.y = pack4(p0[1]);
      w0.z = pack4(p0[2]); w0.w = pack4(p0[3]);
      w1.x = pack4(p1[0]); w1.y = pack4(p1[1]);
      w1.z = pack4(p1[2]); w1.w = pack4(p1[3]);
      *(uint4*)Al0 = w0;
      *(uint4*)Al1 = w1;
      __syncthreads();
      v4i af[4], bf[4];
#pragma unroll
      for (int i = 0; i < 4; ++i) af[i] = *(const v4i*)(aLds + i * 16 * BK);
#pragma unroll
      for (int i = 0; i < 4; ++i) bf[i] = *(const v4i*)(bLds + i * 16 * BK);
#pragma unroll
      for (int mi = 0; mi < 4; ++mi)
#pragma unroll
        for (int ni = 0; ni < 4; ++ni)
          acc[mi][ni] = __builtin_amdgcn_mfma_i32_16x16x64_i8(
              af[mi], bf[ni], acc[mi][ni], 0, 0, 0);
      __syncthreads();
    }
  } else {
    const int8_t* Ag0 = (const int8_t*)Xv + (size_t)(bm * BM + r0) * K_DIM + c0;
    const int8_t* Ag1 = Ag0 + (size_t)64 * K_DIM;
    for (int k0 = 0; k0 < K_DIM; k0 += BK) {
      gll16(Ag0 + k0, Al0);
      gll16(Ag1 + k0, Al1);
      gll16(Bg0 + k0, Bl0);
      gll16(Bg1 + k0, Bl1);
      __syncthreads();
      v4i af[4], bf[4];
#pragma unroll
      for (int i = 0; i < 4; ++i) af[i] = *(const v4i*)(aLds + i * 16 * BK);
#pragma unroll
      for (int i = 0; i < 4; ++i) bf[i] = *(const v4i*)(bLds + i * 16 * BK);
#pragma unroll
      for (int mi = 0; mi < 4; ++mi)
#pragma unroll
        for (int ni = 0; ni < 4; ++ni)
          acc[mi][ni] = __builtin_amdgcn_mfma_i32_16x16x64_i8(
              af[mi], bf[ni], acc[mi][ni], 0, 0, 0);
      __syncthreads();
    }
  }
  epilogue(acc, aScale[0], bScale, Y, bm, bn, wm, wn, quad, l16);
}

extern "C" void kernel_launch(void* const* d_in, const int* in_sizes, int n_in,
                              void* d_out, int out_size, void* d_ws,
                              size_t ws_size, hipStream_t stream) {
  const void* Xv = d_in[0];
  const void* Wv = d_in[1];
  const float* a = (const float*)d_in[2];
  const float* b = (const float*)d_in[3];
  int* Y = (int*)d_out;

  const size_t xB = (size_t)M_DIM * K_DIM;  // 32 MB packed X
  const size_t wB = (size_t)N_DIM * K_DIM;  // 16 MB packed W^T

  if (ws_size >= xB + wB + 64) {
    int8_t* Xp = (int8_t*)d_ws;
    int8_t* WT = (int8_t*)d_ws + xB;
    pack_x_f<<<(M_DIM * K_DIM / 4) / 1024, 256, 0, stream>>>(Xv, (u32*)Xp);
    packT_w_f<<<(K_DIM / 64) * (N_DIM / 64), 256, 0, stream>>>(Wv, WT,
                                                               (const int*)Xv);
    gemm_256<<<(M_DIM / 256) * (N_DIM / 256), 512, 0, stream>>>(Xp, WT, a, b,
                                                                Y);
  } else if (ws_size >= wB + 64) {
    int8_t* WT = (int8_t*)d_ws;
    u32* flag = (u32*)((int8_t*)d_ws + wB);
    detect_i32<<<1, 256, 0, stream>>>((const int*)Xv, flag);
    packT_w_f<<<(K_DIM / 64) * (N_DIM / 64), 256, 0, stream>>>(Wv, WT,
                                                               (const int*)Xv);
    gemm_inA<<<(M_DIM / BM) * (N_DIM / BN), 256, 0, stream>>>(Xv, WT, a, b, Y,
                                                              flag);
  } else {
    int8_t* WT = (int8_t*)d_ws;
    u32* flag = (u32*)((int8_t*)d_ws + (ws_size >= wB + 4 ? wB : 0));
    detect_i32<<<1, 256, 0, stream>>>((const int*)Xv, flag);
    packT_w_f<<<(K_DIM / 64) * (N_DIM / 64), 256, 0, stream>>>(Wv, WT,
                                                               (const int*)Xv);
    gemm_inA<<<(M_DIM / BM) * (N_DIM / BN), 256, 0, stream>>>(Xv, WT, a, b, Y,
                                                              flag);
  }
}

// Round 7
// 412.486 us; speedup vs baseline: 3.2253x; 3.2253x over previous
//
#include <hip/hip_runtime.h>
#include <stdint.h>

#define M_DIM 8192   // BATCH*SEQ = 4*2048
#define N_DIM 4096
#define K_DIM 4096
#define BM 128
#define BN 128
#define BK 64

typedef int v4i __attribute__((ext_vector_type(4)));
typedef unsigned u32;

__device__ __forceinline__ void gll16(const void* g, void* l) {
  __builtin_amdgcn_global_load_lds(
      (const __attribute__((address_space(1))) void*)g,
      (__attribute__((address_space(3))) void*)l, 16, 0, 0);
}

__device__ __forceinline__ u32 pack4(const int4 v) {
  return (v.x & 0xffu) | ((v.y & 0xffu) << 8) | ((v.z & 0xffu) << 16) |
         ((u32)(v.w & 0xffu) << 24);
}

// ---------------------------------------------------------------------------
// Header-based dtype detection: first 4 KB of X is in-bounds under both
// hypotheses; i32 materialization iff every word is a sign-extended int8.
// ---------------------------------------------------------------------------
__device__ __forceinline__ bool hdr_is_i32(const int* __restrict__ X, int tid,
                                           int* ok) {
  if (tid == 0) *ok = 1;
  __syncthreads();
  int good = 1;
  for (int i = tid; i < 1024; i += 256) {
    const int w = X[i];
    good &= (w == (int)(int8_t)(w & 0xff));
  }
  if (!good) atomicAnd(ok, 0);
  __syncthreads();
  return *ok != 0;
}

// Standalone detect (fallback paths only; writes flag for gemm_inA).
__global__ __launch_bounds__(256) void detect_i32(const int* __restrict__ X,
                                                  u32* __restrict__ flag) {
  __shared__ int ok;
  const bool i32 = hdr_is_i32(X, threadIdx.x, &ok);
  if (threadIdx.x == 0) *flag = i32 ? 1u : 0u;
}

// ---------------------------------------------------------------------------
// pack_xw_f: ONE launch for both pack stages (saves a serialized launch gap).
//   blocks [0, 8192):        X -> packed int8 bytes (32 MB out)
//   blocks [8192, 8192+4096): W [K][N] -> WT int8 [N][K], 64x64 tiles
//                             (64 k-tiles x 64 n-tiles = 4096 blocks —
//                              R6 launched only 1024 here: 3/4 of WT was
//                              garbage, absmax 255. Grid fixed in R7.)
// dtype self-detected from X header per block (uniform answer).
// ---------------------------------------------------------------------------
__global__ __launch_bounds__(256) void pack_xw_f(const void* __restrict__ Xin,
                                                 const void* __restrict__ Wv,
                                                 u32* __restrict__ xout,
                                                 int8_t* __restrict__ WT) {
  __shared__ u32 lds[64 * 21];
  __shared__ int ok;
  const int tid = threadIdx.x;
  const bool i32 = hdr_is_i32((const int*)Xin, tid, &ok);

  if (blockIdx.x < 8192) {
    // ---- X pack ----
    const int base = blockIdx.x * 1024 + tid;
    if (i32) {
      const int4* in = (const int4*)Xin;  // 128 MB source (valid when int32)
#pragma unroll
      for (int j = 0; j < 4; ++j) {
        const int idx = base + j * 256;
        xout[idx] = pack4(in[idx]);
      }
    } else {
      const u32* in = (const u32*)Xin;    // 32 MB source (already bytes)
#pragma unroll
      for (int j = 0; j < 4; ++j) {
        const int idx = base + j * 256;
        xout[idx] = in[idx];
      }
    }
    return;
  }

  // ---- W transpose-pack ----
  const int bid = blockIdx.x - 8192;  // [0, 4096)
  const int tk = bid & 63;   // k-tile
  const int tn = bid >> 6;   // n-tile
  const int k0 = tk * 64, n0 = tn * 64;

#pragma unroll
  for (int j = 0; j < 4; ++j) {
    const int id = j * 256 + tid;
    const int k = id >> 4, c = id & 15;
    u32 word;
    if (i32) {
      const int4 v =
          *(const int4*)((const int*)Wv + (size_t)(k0 + k) * N_DIM + n0 + c * 4);
      word = pack4(v);
    } else {
      word = *(const u32*)((const int8_t*)Wv + (size_t)(k0 + k) * N_DIM + n0 +
                           c * 4);
    }
    lds[k * 21 + c] = word;  // bytes of W[k0+k][n0+c*4 .. +4]
  }
  __syncthreads();
  const int kd = tid & 15, nq = tid >> 4;
  const u32 d0 = lds[(kd * 4 + 0) * 21 + nq];
  const u32 d1 = lds[(kd * 4 + 1) * 21 + nq];
  const u32 d2 = lds[(kd * 4 + 2) * 21 + nq];
  const u32 d3 = lds[(kd * 4 + 3) * 21 + nq];
  u32* outp = (u32*)WT;
#pragma unroll
  for (int i = 0; i < 4; ++i) {
    const u32 e = ((d0 >> (8 * i)) & 0xffu) | (((d1 >> (8 * i)) & 0xffu) << 8) |
                  (((d2 >> (8 * i)) & 0xffu) << 16) |
                  (((d3 >> (8 * i)) & 0xffu) << 24);
    const int n = n0 + nq * 4 + i;
    outp[(size_t)n * (K_DIM / 4) + (k0 / 4) + kd] = e;
  }
}

// packT_w_f kept for the ws-constrained fallback paths.
__global__ __launch_bounds__(256) void packT_w_f(const void* __restrict__ Wv,
                                                 int8_t* __restrict__ WT,
                                                 const int* __restrict__ Xhdr) {
  __shared__ u32 lds[64 * 21];
  __shared__ int ok;
  const int tid = threadIdx.x;
  const bool i32 = hdr_is_i32(Xhdr, tid, &ok);
  const int tk = blockIdx.x & 63;
  const int tn = blockIdx.x >> 6;
  const int k0 = tk * 64, n0 = tn * 64;

#pragma unroll
  for (int j = 0; j < 4; ++j) {
    const int id = j * 256 + tid;
    const int k = id >> 4, c = id & 15;
    u32 word;
    if (i32) {
      const int4 v =
          *(const int4*)((const int*)Wv + (size_t)(k0 + k) * N_DIM + n0 + c * 4);
      word = pack4(v);
    } else {
      word = *(const u32*)((const int8_t*)Wv + (size_t)(k0 + k) * N_DIM + n0 +
                           c * 4);
    }
    lds[k * 21 + c] = word;
  }
  __syncthreads();
  const int kd = tid & 15, nq = tid >> 4;
  const u32 d0 = lds[(kd * 4 + 0) * 21 + nq];
  const u32 d1 = lds[(kd * 4 + 1) * 21 + nq];
  const u32 d2 = lds[(kd * 4 + 2) * 21 + nq];
  const u32 d3 = lds[(kd * 4 + 3) * 21 + nq];
  u32* outp = (u32*)WT;
#pragma unroll
  for (int i = 0; i < 4; ++i) {
    const u32 e = ((d0 >> (8 * i)) & 0xffu) | (((d1 >> (8 * i)) & 0xffu) << 8) |
                  (((d2 >> (8 * i)) & 0xffu) << 16) |
                  (((d3 >> (8 * i)) & 0xffu) << 24);
    const int n = n0 + nq * 4 + i;
    outp[(size_t)n * (K_DIM / 4) + (k0 / 4) + kd] = e;
  }
}

// ---------------------------------------------------------------------------
// epilogue (128² fallback): C/D layout col = lane&15, row = quad*4 + reg.
// ---------------------------------------------------------------------------
__device__ __forceinline__ void epilogue(const v4i acc[4][4], float a,
                                         const float* __restrict__ bScale,
                                         int* __restrict__ Y, int bm, int bn,
                                         int wm, int wn, int quad, int l16) {
  const int nBase = bn * BN + wn * 64 + l16;
  float bs[4];
#pragma unroll
  for (int ni = 0; ni < 4; ++ni) bs[ni] = bScale[nBase + ni * 16];
#pragma unroll
  for (int mi = 0; mi < 4; ++mi) {
    const int m0 = bm * BM + wm * 64 + mi * 16 + quad * 4;
#pragma unroll
    for (int r = 0; r < 4; ++r) {
      int* row = Y + (size_t)(m0 + r) * N_DIM + nBase;
#pragma unroll
      for (int ni = 0; ni < 4; ++ni) {
        float v = ((float)acc[mi][ni][r] * a) * bs[ni];
        v = rintf(v);
        v = fminf(fmaxf(v, -128.f), 127.f);
        row[ni * 16] = (int)v;
      }
    }
  }
}

// ---- gemm_256 helpers -----------------------------------------------------
__device__ __forceinline__ void rd4(v4i* f, const int8_t* base, int off) {
#pragma unroll
  for (int i = 0; i < 4; ++i) f[i] = *(const v4i*)(base + off + i * 1024);
}

__device__ __forceinline__ void mfma16(v4i acc[8][4], int row, const v4i* a,
                                       const v4i* b) {
#pragma unroll
  for (int mi = 0; mi < 4; ++mi)
#pragma unroll
    for (int ni = 0; ni < 4; ++ni)
      acc[row + mi][ni] = __builtin_amdgcn_mfma_i32_16x16x64_i8(
          a[mi], b[ni], acc[row + mi][ni], 0, 0, 0);
}

// 64-B sub-slot compute: 12 ds_reads + 32 MFMA (proven R1/R3 fragment path).
__device__ __forceinline__ void compute64(const int8_t* aBase,
                                          const int8_t* bBase, int soff,
                                          v4i acc[8][4]) {
  v4i bf[4], af[4], ag[4];
  rd4(bf, bBase, soff);
  rd4(af, aBase, soff);
  __builtin_amdgcn_s_setprio(1);
  mfma16(acc, 0, af, bf);
  rd4(ag, aBase, soff + 4096);  // second-half A hides under first 16 MFMAs
  mfma16(acc, 4, ag, bf);
  __builtin_amdgcn_s_setprio(0);
}

// ---------------------------------------------------------------------------
// gemm_256: 256x256 tile, 8 waves (2M x 4N), mfma_i32_16x16x64_i8.
// R7 = R6 structure (pack grid fixed): FUSED kstep (BK=128). Two 64-B
// sub-slots computed per {vmcnt + barrier} -> sync count halves (64 -> 32)
// at identical LDS map. R1/R3/R4 measured ~2850 cyc/kstep vs 1306 MFMA
// floor with the gap invariant under intra-kstep reordering -> treat it as
// per-sync fixed overhead and amortize it over 2x the MFMAs.
//  - ring of 4 sub-slots (16 KB each per operand, 128 KB total), ping-pong
//    slot PAIRS: fused step G computes sub-slots {2G,2G+1}&3, stages
//    {2G+2,2G+3}&3 (disjoint). vmcnt(0)+barrier per fused step publishes.
//  - T2 XOR swizzle via pre-swizzled global source + swizzled ds_read.
//  - T5 setprio; T1 bijective XCD swizzle (512%8==0).
// ---------------------------------------------------------------------------
__global__ __launch_bounds__(512, 2) void gemm_256(
    const int8_t* __restrict__ X, const int8_t* __restrict__ WT,
    const float* __restrict__ aScale, const float* __restrict__ bScale,
    int* __restrict__ Y) {
  __shared__ __align__(16) int8_t lds[131072];  // A ring 64KB | B ring 64KB
  const int tid = threadIdx.x;
  const int lane = tid & 63;
  const int wave = tid >> 6;
  const int quad = lane >> 4, l16 = lane & 15;
  const int wm = wave >> 2, wn = wave & 3;  // 2 x 4 wave grid

  // XCD-aware bijective swizzle: nwg=512, 64 blocks/XCD
  const int swzb = (blockIdx.x & 7) * 64 + (blockIdx.x >> 3);
  const int bn = swzb & 15, bm = swzb >> 4;  // bn inner: A-panel reuse per XCD

  // write-side swizzle selector: row = tid>>2  ->  (row>>1)&3 = (tid>>3)&3
  const int clog = (((tid & 3) ^ ((tid >> 3) & 3)) << 4);
  // read-side: row = {wm*128|wn*64} + {mi|ni}*16 + l16 -> (row>>1)&3 = (l16>>1)&3
  const int pc = quad ^ ((l16 >> 1) & 3);

  const int8_t* xa = X + (size_t)(bm * 256 + (tid >> 2)) * K_DIM + clog;
  const int8_t* xb = WT + (size_t)(bn * 256 + (tid >> 2)) * K_DIM + clog;
  int8_t* ldsA = lds + tid * 16;           // linear DMA dest, round1 at +8192
  int8_t* ldsB = lds + 65536 + tid * 16;
  const int8_t* aBase = lds + (wm * 128 + l16) * 64 + pc * 16;
  const int8_t* bBase = lds + 65536 + (wn * 64 + l16) * 64 + pc * 16;

  v4i acc[8][4] = {};

  // prologue: stage sub-slots 0,1 (ksteps 0,1)
#pragma unroll
  for (int t = 0; t < 2; ++t) {
    gll16(xa + t * 64, ldsA + t * 16384);
    gll16(xa + (size_t)128 * K_DIM + t * 64, ldsA + t * 16384 + 8192);
    gll16(xb + t * 64, ldsB + t * 16384);
    gll16(xb + (size_t)128 * K_DIM + t * 64, ldsB + t * 16384 + 8192);
  }
  asm volatile("s_waitcnt vmcnt(0)" ::: "memory");
  __builtin_amdgcn_s_barrier();

  for (int G = 0; G < 32; ++G) {
    const int g0 = 2 * G;
    // stage the OTHER slot pair (ksteps g0+2, g0+3); disjoint from the pair
    // being computed, so issue-early is race-free.
    if (G < 31) {
#pragma unroll
      for (int t = 2; t < 4; ++t) {
        const int poff = ((g0 + t) & 3) << 14;
        const int8_t* sa = xa + (size_t)(g0 + t) * 64;
        const int8_t* sb = xb + (size_t)(g0 + t) * 64;
        gll16(sa, ldsA + poff);
        gll16(sa + (size_t)128 * K_DIM, ldsA + poff + 8192);
        gll16(sb, ldsB + poff);
        gll16(sb + (size_t)128 * K_DIM, ldsB + poff + 8192);
      }
    }
    // two sub-slot computes per sync
    compute64(aBase, bBase, (g0 & 3) << 14, acc);
    compute64(aBase, bBase, ((g0 + 1) & 3) << 14, acc);
    // publish next pair; the full step (~4000+ cyc) covers HBM latency
    asm volatile("s_waitcnt vmcnt(0)" ::: "memory");
    __builtin_amdgcn_s_barrier();
  }

  // ---- epilogue: col = lane&15, row = quad*4 + reg ----
  const float a = aScale[0];
  const int nBase = bn * 256 + wn * 64 + l16;
  float bs[4];
#pragma unroll
  for (int ni = 0; ni < 4; ++ni) bs[ni] = bScale[nBase + ni * 16];
#pragma unroll
  for (int mi = 0; mi < 8; ++mi) {
    const int m0 = bm * 256 + wm * 128 + mi * 16 + quad * 4;
#pragma unroll
    for (int r = 0; r < 4; ++r) {
      int* row = Y + (size_t)(m0 + r) * N_DIM + nBase;
#pragma unroll
      for (int ni = 0; ni < 4; ++ni) {
        float v = ((float)acc[mi][ni][r] * a) * bs[ni];
        v = rintf(v);
        v = fminf(fmaxf(v, -128.f), 127.f);
        row[ni * 16] = (int)v;
      }
    }
  }
}

// ---------------------------------------------------------------------------
// gemm_inA (fallback when ws only fits WT): A read from X (dtype by flag,
// packed in-kernel), B from packed WT. GEMM never writes ws -> no race.
// ---------------------------------------------------------------------------
__global__ __launch_bounds__(256) void gemm_inA(
    const void* __restrict__ Xv, const int8_t* __restrict__ WT,
    const float* __restrict__ aScale, const float* __restrict__ bScale,
    int* __restrict__ Y, const u32* __restrict__ flag) {
  __shared__ __align__(16) int8_t As[BM * BK];
  __shared__ __align__(16) int8_t Bs[BN * BK];
  const bool i32 = (*flag != 0);
  const int tid = threadIdx.x;
  const int lane = tid & 63, wave = tid >> 6;
  const int quad = lane >> 4, l16 = lane & 15;
  const int wm = wave & 1, wn = wave >> 1;
  const int bn = blockIdx.x & 31;
  const int bm = blockIdx.x >> 5;

  const int r0 = tid >> 2;
  const int c0 = (tid & 3) * 16;   // k offset (elements) within BK
  const int8_t* Bg0 = WT + (size_t)(bn * BN + r0) * K_DIM + c0;
  const int8_t* Bg1 = Bg0 + (size_t)64 * K_DIM;
  int8_t* Al0 = As + tid * 16;
  int8_t* Al1 = Al0 + 4096;
  int8_t* Bl0 = Bs + tid * 16;
  int8_t* Bl1 = Bl0 + 4096;

  v4i acc[4][4] = {};
  const int8_t* aLds = As + (wm * 64 + l16) * BK + quad * 16;
  const int8_t* bLds = Bs + (wn * 64 + l16) * BK + quad * 16;

  if (i32) {
    const int* Xg0 = (const int*)Xv + (size_t)(bm * BM + r0) * K_DIM + c0;
    const int* Xg1 = Xg0 + (size_t)64 * K_DIM;
    for (int k0 = 0; k0 < K_DIM; k0 += BK) {
      gll16(Bg0 + k0, Bl0);
      gll16(Bg1 + k0, Bl1);
      const int4* p0 = (const int4*)(Xg0 + k0);
      const int4* p1 = (const int4*)(Xg1 + k0);
      uint4 w0, w1;
      w0.x = pack4(p0[0]); w0.y = pack4(p0[1]);
      w0.z = pack4(p0[2]); w0.w = pack4(p0[3]);
      w1.x = pack4(p1[0]); w1.y = pack4(p1[1]);
      w1.z = pack4(p1[2]); w1.w = pack4(p1[3]);
      *(uint4*)Al0 = w0;
      *(uint4*)Al1 = w1;
      __syncthreads();
      v4i af[4], bf[4];
#pragma unroll
      for (int i = 0; i < 4; ++i) af[i] = *(const v4i*)(aLds + i * 16 * BK);
#pragma unroll
      for (int i = 0; i < 4; ++i) bf[i] = *(const v4i*)(bLds + i * 16 * BK);
#pragma unroll
      for (int mi = 0; mi < 4; ++mi)
#pragma unroll
        for (int ni = 0; ni < 4; ++ni)
          acc[mi][ni] = __builtin_amdgcn_mfma_i32_16x16x64_i8(
              af[mi], bf[ni], acc[mi][ni], 0, 0, 0);
      __syncthreads();
    }
  } else {
    const int8_t* Ag0 = (const int8_t*)Xv + (size_t)(bm * BM + r0) * K_DIM + c0;
    const int8_t* Ag1 = Ag0 + (size_t)64 * K_DIM;
    for (int k0 = 0; k0 < K_DIM; k0 += BK) {
      gll16(Ag0 + k0, Al0);
      gll16(Ag1 + k0, Al1);
      gll16(Bg0 + k0, Bl0);
      gll16(Bg1 + k0, Bl1);
      __syncthreads();
      v4i af[4], bf[4];
#pragma unroll
      for (int i = 0; i < 4; ++i) af[i] = *(const v4i*)(aLds + i * 16 * BK);
#pragma unroll
      for (int i = 0; i < 4; ++i) bf[i] = *(const v4i*)(bLds + i * 16 * BK);
#pragma unroll
      for (int mi = 0; mi < 4; ++mi)
#pragma unroll
        for (int ni = 0; ni < 4; ++ni)
          acc[mi][ni] = __builtin_amdgcn_mfma_i32_16x16x64_i8(
              af[mi], bf[ni], acc[mi][ni], 0, 0, 0);
      __syncthreads();
    }
  }
  epilogue(acc, aScale[0], bScale, Y, bm, bn, wm, wn, quad, l16);
}

extern "C" void kernel_launch(void* const* d_in, const int* in_sizes, int n_in,
                              void* d_out, int out_size, void* d_ws,
                              size_t ws_size, hipStream_t stream) {
  const void* Xv = d_in[0];
  const void* Wv = d_in[1];
  const float* a = (const float*)d_in[2];
  const float* b = (const float*)d_in[3];
  int* Y = (int*)d_out;

  const size_t xB = (size_t)M_DIM * K_DIM;  // 32 MB packed X
  const size_t wB = (size_t)N_DIM * K_DIM;  // 16 MB packed W^T

  if (ws_size >= xB + wB + 64) {
    int8_t* Xp = (int8_t*)d_ws;
    int8_t* WT = (int8_t*)d_ws + xB;
    pack_xw_f<<<8192 + (K_DIM / 64) * (N_DIM / 64), 256, 0, stream>>>(
        Xv, Wv, (u32*)Xp, WT);
    gemm_256<<<(M_DIM / 256) * (N_DIM / 256), 512, 0, stream>>>(Xp, WT, a, b,
                                                                Y);
  } else if (ws_size >= wB + 64) {
    int8_t* WT = (int8_t*)d_ws;
    u32* flag = (u32*)((int8_t*)d_ws + wB);
    detect_i32<<<1, 256, 0, stream>>>((const int*)Xv, flag);
    packT_w_f<<<(K_DIM / 64) * (N_DIM / 64), 256, 0, stream>>>(Wv, WT,
                                                               (const int*)Xv);
    gemm_inA<<<(M_DIM / BM) * (N_DIM / BN), 256, 0, stream>>>(Xv, WT, a, b, Y,
                                                              flag);
  } else {
    int8_t* WT = (int8_t*)d_ws;
    u32* flag = (u32*)((int8_t*)d_ws + (ws_size >= wB + 4 ? wB : 0));
    detect_i32<<<1, 256, 0, stream>>>((const int*)Xv, flag);
    packT_w_f<<<(K_DIM / 64) * (N_DIM / 64), 256, 0, stream>>>(Wv, WT,
                                                               (const int*)Xv);
    gemm_inA<<<(M_DIM / BM) * (N_DIM / BN), 256, 0, stream>>>(Xv, WT, a, b, Y,
                                                              flag);
  }
}

// Round 8
// 389.351 us; speedup vs baseline: 3.4169x; 1.0594x over previous
//
#include <hip/hip_runtime.h>
#include <stdint.h>

#define M_DIM 8192   // BATCH*SEQ = 4*2048
#define N_DIM 4096
#define K_DIM 4096
#define BM 128
#define BN 128
#define BK 64

typedef int v4i __attribute__((ext_vector_type(4)));
typedef unsigned u32;

__device__ __forceinline__ void gll16(const void* g, void* l) {
  __builtin_amdgcn_global_load_lds(
      (const __attribute__((address_space(1))) void*)g,
      (__attribute__((address_space(3))) void*)l, 16, 0, 0);
}

__device__ __forceinline__ u32 pack4(const int4 v) {
  return (v.x & 0xffu) | ((v.y & 0xffu) << 8) | ((v.z & 0xffu) << 16) |
         ((u32)(v.w & 0xffu) << 24);
}

// Bank-swizzle applied AT PACK TIME: within each 128-B segment of a row,
// logical 16-B chunk c is stored at c ^ (row & 7). u32-index form:
__device__ __forceinline__ size_t swz_idx(size_t i) {
  return i ^ ((((u32)(i >> 10)) & 7u) << 2);
}

// ---------------------------------------------------------------------------
// Header-based dtype detection: first 4 KB of X is in-bounds under both
// hypotheses; i32 materialization iff every int32 word is sign-extended int8.
// ---------------------------------------------------------------------------
__device__ __forceinline__ bool hdr_is_i32(const int* __restrict__ X, int tid,
                                           int* ok) {
  if (tid == 0) *ok = 1;
  __syncthreads();
  int good = 1;
  for (int i = tid; i < 1024; i += 256) {
    const int w = X[i];
    good &= (w == (int)(int8_t)(w & 0xff));
  }
  if (!good) atomicAnd(ok, 0);
  __syncthreads();
  return *ok != 0;
}

__global__ __launch_bounds__(256) void detect_i32(const int* __restrict__ X,
                                                  u32* __restrict__ flag) {
  __shared__ int ok;
  const bool i32 = hdr_is_i32(X, threadIdx.x, &ok);
  if (threadIdx.x == 0) *flag = i32 ? 1u : 0u;
}

// ---------------------------------------------------------------------------
// pack_xw_f: ONE launch for both pack stages. Outputs are SWIZZLED (swz_idx)
// so the GEMM's global_load_lds reads plain contiguous 128-B lines.
//   blocks [0, 8192):         X -> packed+swizzled int8 bytes (32 MB)
//   blocks [8192, 8192+4096): W [K][N] -> WT int8 [N][K] packed+swizzled
// ---------------------------------------------------------------------------
__global__ __launch_bounds__(256) void pack_xw_f(const void* __restrict__ Xin,
                                                 const void* __restrict__ Wv,
                                                 u32* __restrict__ xout,
                                                 int8_t* __restrict__ WT) {
  __shared__ u32 lds[64 * 21];
  __shared__ int ok;
  const int tid = threadIdx.x;
  const bool i32 = hdr_is_i32((const int*)Xin, tid, &ok);

  if (blockIdx.x < 8192) {
    // ---- X pack (store swizzled) ----
    const int base = blockIdx.x * 1024 + tid;
    if (i32) {
      const int4* in = (const int4*)Xin;  // 128 MB source (valid when int32)
#pragma unroll
      for (int j = 0; j < 4; ++j) {
        const int idx = base + j * 256;
        xout[swz_idx((size_t)idx)] = pack4(in[idx]);
      }
    } else {
      const u32* in = (const u32*)Xin;    // 32 MB source (already bytes)
#pragma unroll
      for (int j = 0; j < 4; ++j) {
        const int idx = base + j * 256;
        xout[swz_idx((size_t)idx)] = in[idx];
      }
    }
    return;
  }

  // ---- W transpose-pack (store swizzled) ----
  const int bid = blockIdx.x - 8192;  // [0, 4096)
  const int tk = bid & 63;   // k-tile
  const int tn = bid >> 6;   // n-tile
  const int k0 = tk * 64, n0 = tn * 64;

#pragma unroll
  for (int j = 0; j < 4; ++j) {
    const int id = j * 256 + tid;
    const int k = id >> 4, c = id & 15;
    u32 word;
    if (i32) {
      const int4 v =
          *(const int4*)((const int*)Wv + (size_t)(k0 + k) * N_DIM + n0 + c * 4);
      word = pack4(v);
    } else {
      word = *(const u32*)((const int8_t*)Wv + (size_t)(k0 + k) * N_DIM + n0 +
                           c * 4);
    }
    lds[k * 21 + c] = word;  // bytes of W[k0+k][n0+c*4 .. +4]
  }
  __syncthreads();
  const int kd = tid & 15, nq = tid >> 4;
  const u32 d0 = lds[(kd * 4 + 0) * 21 + nq];
  const u32 d1 = lds[(kd * 4 + 1) * 21 + nq];
  const u32 d2 = lds[(kd * 4 + 2) * 21 + nq];
  const u32 d3 = lds[(kd * 4 + 3) * 21 + nq];
  u32* outp = (u32*)WT;
#pragma unroll
  for (int i = 0; i < 4; ++i) {
    const u32 e = ((d0 >> (8 * i)) & 0xffu) | (((d1 >> (8 * i)) & 0xffu) << 8) |
                  (((d2 >> (8 * i)) & 0xffu) << 16) |
                  (((d3 >> (8 * i)) & 0xffu) << 24);
    const int n = n0 + nq * 4 + i;
    outp[swz_idx((size_t)n * (K_DIM / 4) + (k0 / 4) + kd)] = e;
  }
}

// packT_w_f: LINEAR layout — used only by the ws-constrained fallback paths.
__global__ __launch_bounds__(256) void packT_w_f(const void* __restrict__ Wv,
                                                 int8_t* __restrict__ WT,
                                                 const int* __restrict__ Xhdr) {
  __shared__ u32 lds[64 * 21];
  __shared__ int ok;
  const int tid = threadIdx.x;
  const bool i32 = hdr_is_i32(Xhdr, tid, &ok);
  const int tk = blockIdx.x & 63;
  const int tn = blockIdx.x >> 6;
  const int k0 = tk * 64, n0 = tn * 64;

#pragma unroll
  for (int j = 0; j < 4; ++j) {
    const int id = j * 256 + tid;
    const int k = id >> 4, c = id & 15;
    u32 word;
    if (i32) {
      const int4 v =
          *(const int4*)((const int*)Wv + (size_t)(k0 + k) * N_DIM + n0 + c * 4);
      word = pack4(v);
    } else {
      word = *(const u32*)((const int8_t*)Wv + (size_t)(k0 + k) * N_DIM + n0 +
                           c * 4);
    }
    lds[k * 21 + c] = word;
  }
  __syncthreads();
  const int kd = tid & 15, nq = tid >> 4;
  const u32 d0 = lds[(kd * 4 + 0) * 21 + nq];
  const u32 d1 = lds[(kd * 4 + 1) * 21 + nq];
  const u32 d2 = lds[(kd * 4 + 2) * 21 + nq];
  const u32 d3 = lds[(kd * 4 + 3) * 21 + nq];
  u32* outp = (u32*)WT;
#pragma unroll
  for (int i = 0; i < 4; ++i) {
    const u32 e = ((d0 >> (8 * i)) & 0xffu) | (((d1 >> (8 * i)) & 0xffu) << 8) |
                  (((d2 >> (8 * i)) & 0xffu) << 16) |
                  (((d3 >> (8 * i)) & 0xffu) << 24);
    const int n = n0 + nq * 4 + i;
    outp[(size_t)n * (K_DIM / 4) + (k0 / 4) + kd] = e;
  }
}

// ---------------------------------------------------------------------------
// epilogue (128² fallback): C/D layout col = lane&15, row = quad*4 + reg.
// ---------------------------------------------------------------------------
__device__ __forceinline__ void epilogue(const v4i acc[4][4], float a,
                                         const float* __restrict__ bScale,
                                         int* __restrict__ Y, int bm, int bn,
                                         int wm, int wn, int quad, int l16) {
  const int nBase = bn * BN + wn * 64 + l16;
  float bs[4];
#pragma unroll
  for (int ni = 0; ni < 4; ++ni) bs[ni] = bScale[nBase + ni * 16];
#pragma unroll
  for (int mi = 0; mi < 4; ++mi) {
    const int m0 = bm * BM + wm * 64 + mi * 16 + quad * 4;
#pragma unroll
    for (int r = 0; r < 4; ++r) {
      int* row = Y + (size_t)(m0 + r) * N_DIM + nBase;
#pragma unroll
      for (int ni = 0; ni < 4; ++ni) {
        float v = ((float)acc[mi][ni][r] * a) * bs[ni];
        v = rintf(v);
        v = fminf(fmaxf(v, -128.f), 127.f);
        row[ni * 16] = (int)v;
      }
    }
  }
}

__device__ __forceinline__ void mfma16(v4i acc[8][4], int row, const v4i* a,
                                       const v4i* b) {
#pragma unroll
  for (int mi = 0; mi < 4; ++mi)
#pragma unroll
    for (int ni = 0; ni < 4; ++ni)
      acc[row + mi][ni] = __builtin_amdgcn_mfma_i32_16x16x64_i8(
          a[mi], b[ni], acc[row + mi][ni], 0, 0, 0);
}

// ---------------------------------------------------------------------------
// gemm_256: 256x256 tile, 8 waves (2M x 4N), mfma_i32_16x16x64_i8.
// R8 change: K-tile = 128 B/row -> every gll16 site covers full 128-B cache
// lines (8 threads/row). All R1-R7 variants staged 64-B row pieces and
// pinned at ~11 B/cyc/CU DMA; the bf16 8-phase reference (128-B pieces,
// same tile/LDS/occupancy) sustains 20.5 B/cyc -> request-width theory.
//  - inputs pre-swizzled at pack time (swz_idx): gll16 reads LINEAR global,
//    writes LINEAR LDS; ds_read applies chunk XOR c^(row&7) (T2, bijective
//    per row -> conflict-free).
//  - LDS: per operand 8 quarter-slots x 8 KB (64 rows x 128 B) = 64 KB;
//    slot(tile T, quarter q) = (4T + q) & 7. A quarter q = wm*2 + (mi>=4);
//    B quarter = wn.
//  - 4 phases/K-tile: p0(kh0,mi0-3 +B kh0), p1(kh0,mi4-7), p2(kh1,mi0-3
//    +B kh1), p3(kh1,mi4-7). Stage T+1 spread across phases:
//    p0: Bq0,Bq1; p1: Bq2,Bq3; p2: Aq0,Aq2; p3: Aq1,Aq3.
//  - counted vmcnt(2) at ends of p0 and p3 only (never 0 until tail):
//    end-p3 needs all-B + A{q0,q2} of next tile (6 oldest of 8);
//    end-p0 needs A{q1,q3} (2 oldest of 4).
//  - T5 setprio; T1 bijective XCD swizzle (512%8==0).
// ---------------------------------------------------------------------------
__global__ __launch_bounds__(512, 2) void gemm_256(
    const int8_t* __restrict__ X, const int8_t* __restrict__ WT,
    const float* __restrict__ aScale, const float* __restrict__ bScale,
    int* __restrict__ Y) {
  __shared__ __align__(16) int8_t lds[131072];  // A: 8x8KB @0 | B @65536
  const int tid = threadIdx.x;
  const int lane = tid & 63;
  const int wave = tid >> 6;
  const int quad = lane >> 4, l16 = lane & 15;
  const int wm = wave >> 2, wn = wave & 3;  // 2 x 4 wave grid

  // XCD-aware bijective swizzle: nwg=512, 64 blocks/XCD
  const int swzb = (blockIdx.x & 7) * 64 + (blockIdx.x >> 3);
  const int bn = swzb & 15, bm = swzb >> 4;

  // stage sources: LINEAR (inputs pre-swizzled at pack time)
  // thread tid -> row tid>>3 (64 rows/site), byte (tid&7)*16 within 128-B seg
  const int8_t* xa =
      X + (size_t)(bm * 256 + (tid >> 3)) * K_DIM + (tid & 7) * 16;
  const int8_t* xb =
      WT + (size_t)(bn * 256 + (tid >> 3)) * K_DIM + (tid & 7) * 16;
  int8_t* ldsA = lds + tid * 16;
  int8_t* ldsB = lds + 65536 + tid * 16;

  // ds_read lane constants: logical chunk kh*4+quad, phys = log ^ (row&7),
  // row&7 = l16&7 (row_local = (mi&3)*16 + l16 / ni*16 + l16)
  const int ck0 = ((quad ^ (l16 & 7)) << 4);
  const int ck1 = (((4 | quad) ^ (l16 & 7)) << 4);
  const int8_t* aR = lds + l16 * 128;
  const int8_t* bR = lds + 65536 + l16 * 128;

  v4i acc[8][4] = {};

  // prologue: stage tile 0 in steady-state order (slots 0..3 per operand)
  gll16(xb + 0 * 262144, ldsB + 0 * 8192);   // B q0
  gll16(xb + 1 * 262144, ldsB + 1 * 8192);   // B q1
  gll16(xb + 2 * 262144, ldsB + 2 * 8192);   // B q2
  gll16(xb + 3 * 262144, ldsB + 3 * 8192);   // B q3
  gll16(xa + 0 * 262144, ldsA + 0 * 8192);   // A q0
  gll16(xa + 2 * 262144, ldsA + 2 * 8192);   // A q2
  gll16(xa + 1 * 262144, ldsA + 1 * 8192);   // A q1
  gll16(xa + 3 * 262144, ldsA + 3 * 8192);   // A q3
  asm volatile("s_waitcnt vmcnt(2)" ::: "memory");  // all-B + Aq0,Aq2 landed
  __builtin_amdgcn_s_barrier();

  for (int T = 0; T < 32; ++T) {
    const int sb = (T & 1) * 4;           // this tile's slot base
    const int sA0 = (sb + wm * 2) * 8192;
    const int sA1 = (sb + wm * 2 + 1) * 8192;
    const int sB = (sb + wn) * 8192;
    const int pB = (sb ^ 4) * 8192;       // next tile's slot base
    const size_t tOff = (size_t)(T + 1) * 128;
    const bool st = (T < 31);
    v4i af[4], bf[4];

    // ---- phase 0: kh0, mi 0-3 (+ B kh0); stage B q0,q1 of T+1 ----
#pragma unroll
    for (int i = 0; i < 4; ++i)
      af[i] = *(const v4i*)(aR + sA0 + i * 2048 + ck0);
#pragma unroll
    for (int n = 0; n < 4; ++n)
      bf[n] = *(const v4i*)(bR + sB + n * 2048 + ck0);
    if (st) {
      gll16(xb + tOff, ldsB + pB);
      gll16(xb + 262144 + tOff, ldsB + pB + 8192);
    }
    __builtin_amdgcn_s_barrier();
    asm volatile("s_waitcnt lgkmcnt(0)" ::: "memory");
    __builtin_amdgcn_sched_barrier(0);
    __builtin_amdgcn_s_setprio(1);
    mfma16(acc, 0, af, bf);
    __builtin_amdgcn_s_setprio(0);
    // retire this tile's A q1,q3 (oldest); keep next B q0,q1 in flight
    if (st)
      asm volatile("s_waitcnt vmcnt(2)" ::: "memory");
    else
      asm volatile("s_waitcnt vmcnt(0)" ::: "memory");
    __builtin_amdgcn_s_barrier();

    // ---- phase 1: kh0, mi 4-7; stage B q2,q3 of T+1 ----
#pragma unroll
    for (int i = 0; i < 4; ++i)
      af[i] = *(const v4i*)(aR + sA1 + i * 2048 + ck0);
    if (st) {
      gll16(xb + 2 * 262144 + tOff, ldsB + pB + 2 * 8192);
      gll16(xb + 3 * 262144 + tOff, ldsB + pB + 3 * 8192);
    }
    __builtin_amdgcn_s_barrier();
    asm volatile("s_waitcnt lgkmcnt(0)" ::: "memory");
    __builtin_amdgcn_sched_barrier(0);
    __builtin_amdgcn_s_setprio(1);
    mfma16(acc, 4, af, bf);
    __builtin_amdgcn_s_setprio(0);
    __builtin_amdgcn_s_barrier();

    // ---- phase 2: kh1, mi 0-3 (+ B kh1); stage A q0,q2 of T+1 ----
#pragma unroll
    for (int i = 0; i < 4; ++i)
      af[i] = *(const v4i*)(aR + sA0 + i * 2048 + ck1);
#pragma unroll
    for (int n = 0; n < 4; ++n)
      bf[n] = *(const v4i*)(bR + sB + n * 2048 + ck1);
    if (st) {
      gll16(xa + tOff, ldsA + pB);
      gll16(xa + 2 * 262144 + tOff, ldsA + pB + 2 * 8192);
    }
    __builtin_amdgcn_s_barrier();
    asm volatile("s_waitcnt lgkmcnt(0)" ::: "memory");
    __builtin_amdgcn_sched_barrier(0);
    __builtin_amdgcn_s_setprio(1);
    mfma16(acc, 0, af, bf);
    __builtin_amdgcn_s_setprio(0);
    __builtin_amdgcn_s_barrier();

    // ---- phase 3: kh1, mi 4-7; stage A q1,q3 of T+1 ----
#pragma unroll
    for (int i = 0; i < 4; ++i)
      af[i] = *(const v4i*)(aR + sA1 + i * 2048 + ck1);
    if (st) {
      gll16(xa + 262144 + tOff, ldsA + pB + 8192);
      gll16(xa + 3 * 262144 + tOff, ldsA + pB + 3 * 8192);
    }
    __builtin_amdgcn_s_barrier();
    asm volatile("s_waitcnt lgkmcnt(0)" ::: "memory");
    __builtin_amdgcn_sched_barrier(0);
    __builtin_amdgcn_s_setprio(1);
    mfma16(acc, 4, af, bf);
    __builtin_amdgcn_s_setprio(0);
    if (st) {
      // next tile needs all-B + A q0,q2 (6 oldest of 8 in flight)
      asm volatile("s_waitcnt vmcnt(2)" ::: "memory");
      __builtin_amdgcn_s_barrier();
    }
  }

  // ---- epilogue: col = lane&15, row = quad*4 + reg ----
  const float a = aScale[0];
  const int nBase = bn * 256 + wn * 64 + l16;
  float bs[4];
#pragma unroll
  for (int ni = 0; ni < 4; ++ni) bs[ni] = bScale[nBase + ni * 16];
#pragma unroll
  for (int mi = 0; mi < 8; ++mi) {
    const int m0 = bm * 256 + wm * 128 + mi * 16 + quad * 4;
#pragma unroll
    for (int r = 0; r < 4; ++r) {
      int* row = Y + (size_t)(m0 + r) * N_DIM + nBase;
#pragma unroll
      for (int ni = 0; ni < 4; ++ni) {
        float v = ((float)acc[mi][ni][r] * a) * bs[ni];
        v = rintf(v);
        v = fminf(fmaxf(v, -128.f), 127.f);
        row[ni * 16] = (int)v;
      }
    }
  }
}

// ---------------------------------------------------------------------------
// gemm_inA (fallback when ws only fits WT): A read from X (dtype by flag,
// packed in-kernel), B from LINEAR packed WT. GEMM never writes ws.
// ---------------------------------------------------------------------------
__global__ __launch_bounds__(256) void gemm_inA(
    const void* __restrict__ Xv, const int8_t* __restrict__ WT,
    const float* __restrict__ aScale, const float* __restrict__ bScale,
    int* __restrict__ Y, const u32* __restrict__ flag) {
  __shared__ __align__(16) int8_t As[BM * BK];
  __shared__ __align__(16) int8_t Bs[BN * BK];
  const bool i32 = (*flag != 0);
  const int tid = threadIdx.x;
  const int lane = tid & 63, wave = tid >> 6;
  const int quad = lane >> 4, l16 = lane & 15;
  const int wm = wave & 1, wn = wave >> 1;
  const int bn = blockIdx.x & 31;
  const int bm = blockIdx.x >> 5;

  const int r0 = tid >> 2;
  const int c0 = (tid & 3) * 16;
  const int8_t* Bg0 = WT + (size_t)(bn * BN + r0) * K_DIM + c0;
  const int8_t* Bg1 = Bg0 + (size_t)64 * K_DIM;
  int8_t* Al0 = As + tid * 16;
  int8_t* Al1 = Al0 + 4096;
  int8_t* Bl0 = Bs + tid * 16;
  int8_t* Bl1 = Bl0 + 4096;

  v4i acc[4][4] = {};
  const int8_t* aLds = As + (wm * 64 + l16) * BK + quad * 16;
  const int8_t* bLds = Bs + (wn * 64 + l16) * BK + quad * 16;

  if (i32) {
    const int* Xg0 = (const int*)Xv + (size_t)(bm * BM + r0) * K_DIM + c0;
    const int* Xg1 = Xg0 + (size_t)64 * K_DIM;
    for (int k0 = 0; k0 < K_DIM; k0 += BK) {
      gll16(Bg0 + k0, Bl0);
      gll16(Bg1 + k0, Bl1);
      const int4* p0 = (const int4*)(Xg0 + k0);
      const int4* p1 = (const int4*)(Xg1 + k0);
      uint4 w0, w1;
      w0.x = pack4(p0[0]); w0.y = pack4(p0[1]);
      w0.z = pack4(p0[2]); w0.w = pack4(p0[3]);
      w1.x = pack4(p1[0]); w1.y = pack4(p1[1]);
      w1.z = pack4(p1[2]); w1.w = pack4(p1[3]);
      *(uint4*)Al0 = w0;
      *(uint4*)Al1 = w1;
      __syncthreads();
      v4i af[4], bf[4];
#pragma unroll
      for (int i = 0; i < 4; ++i) af[i] = *(const v4i*)(aLds + i * 16 * BK);
#pragma unroll
      for (int i = 0; i < 4; ++i) bf[i] = *(const v4i*)(bLds + i * 16 * BK);
#pragma unroll
      for (int mi = 0; mi < 4; ++mi)
#pragma unroll
        for (int ni = 0; ni < 4; ++ni)
          acc[mi][ni] = __builtin_amdgcn_mfma_i32_16x16x64_i8(
              af[mi], bf[ni], acc[mi][ni], 0, 0, 0);
      __syncthreads();
    }
  } else {
    const int8_t* Ag0 = (const int8_t*)Xv + (size_t)(bm * BM + r0) * K_DIM + c0;
    const int8_t* Ag1 = Ag0 + (size_t)64 * K_DIM;
    for (int k0 = 0; k0 < K_DIM; k0 += BK) {
      gll16(Ag0 + k0, Al0);
      gll16(Ag1 + k0, Al1);
      gll16(Bg0 + k0, Bl0);
      gll16(Bg1 + k0, Bl1);
      __syncthreads();
      v4i af[4], bf[4];
#pragma unroll
      for (int i = 0; i < 4; ++i) af[i] = *(const v4i*)(aLds + i * 16 * BK);
#pragma unroll
      for (int i = 0; i < 4; ++i) bf[i] = *(const v4i*)(bLds + i * 16 * BK);
#pragma unroll
      for (int mi = 0; mi < 4; ++mi)
#pragma unroll
        for (int ni = 0; ni < 4; ++ni)
          acc[mi][ni] = __builtin_amdgcn_mfma_i32_16x16x64_i8(
              af[mi], bf[ni], acc[mi][ni], 0, 0, 0);
      __syncthreads();
    }
  }
  epilogue(acc, aScale[0], bScale, Y, bm, bn, wm, wn, quad, l16);
}

extern "C" void kernel_launch(void* const* d_in, const int* in_sizes, int n_in,
                              void* d_out, int out_size, void* d_ws,
                              size_t ws_size, hipStream_t stream) {
  const void* Xv = d_in[0];
  const void* Wv = d_in[1];
  const float* a = (const float*)d_in[2];
  const float* b = (const float*)d_in[3];
  int* Y = (int*)d_out;

  const size_t xB = (size_t)M_DIM * K_DIM;  // 32 MB packed X
  const size_t wB = (size_t)N_DIM * K_DIM;  // 16 MB packed W^T

  if (ws_size >= xB + wB + 64) {
    int8_t* Xp = (int8_t*)d_ws;
    int8_t* WT = (int8_t*)d_ws + xB;
    pack_xw_f<<<8192 + (K_DIM / 64) * (N_DIM / 64), 256, 0, stream>>>(
        Xv, Wv, (u32*)Xp, WT);
    gemm_256<<<(M_DIM / 256) * (N_DIM / 256), 512, 0, stream>>>(Xp, WT, a, b,
                                                                Y);
  } else if (ws_size >= wB + 64) {
    int8_t* WT = (int8_t*)d_ws;
    u32* flag = (u32*)((int8_t*)d_ws + wB);
    detect_i32<<<1, 256, 0, stream>>>((const int*)Xv, flag);
    packT_w_f<<<(K_DIM / 64) * (N_DIM / 64), 256, 0, stream>>>(Wv, WT,
                                                               (const int*)Xv);
    gemm_inA<<<(M_DIM / BM) * (N_DIM / BN), 256, 0, stream>>>(Xv, WT, a, b, Y,
                                                              flag);
  } else {
    int8_t* WT = (int8_t*)d_ws;
    u32* flag = (u32*)((int8_t*)d_ws + (ws_size >= wB + 4 ? wB : 0));
    detect_i32<<<1, 256, 0, stream>>>((const int*)Xv, flag);
    packT_w_f<<<(K_DIM / 64) * (N_DIM / 64), 256, 0, stream>>>(Wv, WT,
                                                               (const int*)Xv);
    gemm_inA<<<(M_DIM / BM) * (N_DIM / BN), 256, 0, stream>>>(Xv, WT, a, b, Y,
                                                              flag);
  }
}